// Round 1
// baseline (103.378 us; speedup 1.0000x reference)
//
#include <hip/hip_runtime.h>
#include <cstddef>

namespace {

constexpr int kB = 32, kT = 512, kD = 64, kP = 16, kNW = 63, kDM = 512;
constexpr int kRows = kD * kNW + kT;     // 4544 output rows per batch
constexpr int kTT = 16;                  // t-rows per feature block
constexpr int kNBT = kB * kD;            // 2048 temporal blocks
constexpr int kNBF = kB * (kT / kTT);    // 1024 feature blocks

__global__ __launch_bounds__(512)
void patch_embed(const float* __restrict__ x,
                 const float* __restrict__ Wt,
                 const float* __restrict__ bt,
                 const float* __restrict__ Wd,
                 const float* __restrict__ bd,
                 float* __restrict__ out)
{
    __shared__ float xs[kTT * kD];   // 4 KB, used by both branches
    const int m = threadIdx.x;       // output channel, 0..511
    int blk = blockIdx.x;

    if (blk < kNBT) {
        // ---------------- temporal: out[b, d*63+w, m] = sum_p x[b,8w+p,d]*Wt[m,p] + bt[m]
        const int b = blk >> 6;          // / kD
        const int d = blk & (kD - 1);

        // stage x[b, t, d] for t=0..511 (uncoalesced gather, but x is L2-hot & tiny)
        xs[m] = x[(size_t)(b * kT + m) * kD + d];

        const float4* wtp = (const float4*)(Wt + m * kP);
        const float4 q0 = wtp[0], q1 = wtp[1], q2 = wtp[2], q3 = wtp[3];
        const float bias = bt[m];
        __syncthreads();

        size_t obase = (size_t)b * kRows * kDM + (size_t)(d * kNW) * kDM + m;
        const float4* xv = (const float4*)xs;

        // sliding 16-float window in registers; 2 broadcast b128 reads per step
        float4 c0 = xv[0], c1 = xv[1], c2 = xv[2], c3 = xv[3];
        #pragma unroll
        for (int w = 0; w < kNW; ++w) {
            float a0 = c0.x * q0.x + c0.y * q0.y;
            float a1 = c0.z * q0.z + c0.w * q0.w;
            float a2 = c1.x * q1.x + c1.y * q1.y;
            float a3 = c1.z * q1.z + c1.w * q1.w;
            a0 += c2.x * q2.x + c2.y * q2.y;
            a1 += c2.z * q2.z + c2.w * q2.w;
            a2 += c3.x * q3.x + c3.y * q3.y;
            a3 += c3.z * q3.z + c3.w * q3.w;
            float acc = bias + ((a0 + a1) + (a2 + a3));
            __builtin_nontemporal_store(acc, out + obase + (size_t)w * kDM);
            if (w < kNW - 1) {
                c0 = c2; c1 = c3;
                c2 = xv[2 * w + 4];
                c3 = xv[2 * w + 5];
            }
        }
    } else {
        // ---------------- feature: out[b, 4032+t, m] = sum_d x[b,t,d]*Wd[m,d] + bd[m]
        blk -= kNBT;
        const int b  = blk >> 5;                 // / (kT/kTT)
        const int t0 = (blk & 31) * kTT;

        // stage x[b, t0:t0+16, :] — contiguous, coalesced
        for (int f = m; f < kTT * kD; f += 512)
            xs[f] = x[(size_t)(b * kT + t0) * kD + f];

        // Wd row in registers: 64 floats/thread, amortized over 16 output rows
        float wr[kD];
        const float4* wdp = (const float4*)(Wd + (size_t)m * kD);
        #pragma unroll
        for (int i = 0; i < kD / 4; ++i) {
            float4 v = wdp[i];
            wr[4*i+0] = v.x; wr[4*i+1] = v.y; wr[4*i+2] = v.z; wr[4*i+3] = v.w;
        }
        const float bias = bd[m];
        __syncthreads();

        size_t obase = (size_t)b * kRows * kDM + (size_t)(kD * kNW + t0) * kDM + m;
        for (int tt = 0; tt < kTT; ++tt) {
            const float4* xp = (const float4*)(xs + tt * kD);
            float a0 = 0.f, a1 = 0.f, a2 = 0.f, a3 = 0.f;
            #pragma unroll
            for (int i = 0; i < kD / 4; ++i) {
                float4 v = xp[i];
                a0 += v.x * wr[4*i+0];
                a1 += v.y * wr[4*i+1];
                a2 += v.z * wr[4*i+2];
                a3 += v.w * wr[4*i+3];
            }
            float acc = bias + ((a0 + a1) + (a2 + a3));
            __builtin_nontemporal_store(acc, out + obase + (size_t)tt * kDM);
        }
    }
}

} // namespace

extern "C" void kernel_launch(void* const* d_in, const int* in_sizes, int n_in,
                              void* d_out, int out_size, void* d_ws, size_t ws_size,
                              hipStream_t stream) {
    const float* x  = (const float*)d_in[0];
    const float* Wt = (const float*)d_in[1];
    const float* bt = (const float*)d_in[2];
    const float* Wd = (const float*)d_in[3];
    const float* bd = (const float*)d_in[4];
    float* out = (float*)d_out;

    dim3 grid(kNBT + kNBF);
    dim3 block(512);
    hipLaunchKernelGGL(patch_embed, grid, block, 0, stream, x, Wt, bt, Wd, bd, out);
}